// Round 1
// baseline (136.345 us; speedup 1.0000x reference)
//
#include <hip/hip_runtime.h>
#include <hip/hip_bf16.h>

// Embedding lookup: out[row, :] = weight[ids[row], :]
// ids: 4*2048 = 8192 int32, weight: 32000 x 768 fp32, out: 8192 x 768 fp32.
// One block per row; 192 threads/block (3 waves), one float4 per thread
// (768 floats = 192 float4). Fully coalesced 16B/lane.

#define DIM 768
#define DIM_VEC (DIM / 4)   // 192

__global__ __launch_bounds__(DIM_VEC) void embed_gather_kernel(
    const int* __restrict__ ids,
    const float* __restrict__ weight,
    float* __restrict__ out) {
    const int row = blockIdx.x;
    const int id = ids[row];  // block-uniform -> scalar load
    const float4* __restrict__ src =
        reinterpret_cast<const float4*>(weight) + (size_t)id * DIM_VEC;
    float4* __restrict__ dst =
        reinterpret_cast<float4*>(out) + (size_t)row * DIM_VEC;
    dst[threadIdx.x] = src[threadIdx.x];
}

extern "C" void kernel_launch(void* const* d_in, const int* in_sizes, int n_in,
                              void* d_out, int out_size, void* d_ws, size_t ws_size,
                              hipStream_t stream) {
    const int* ids = (const int*)d_in[0];       // 8192 int32
    const float* weight = (const float*)d_in[1];// 32000*768 fp32
    float* out = (float*)d_out;                 // 8192*768 fp32

    const int n_rows = in_sizes[0];             // 8192
    embed_gather_kernel<<<n_rows, DIM_VEC, 0, stream>>>(ids, weight, out);
}